// Round 2
// baseline (269.682 us; speedup 1.0000x reference)
//
#include <hip/hip_runtime.h>
#include <hip/hip_bf16.h>
#include <stdint.h>

// Problem constants (from reference): B=2048, C=200, F=32, H=256.
// All tensors are float32 (per reference). M = B*C = 409600 rows of 32 feats.
#define M_ROWS 409600
#define C_CNT  200

typedef __attribute__((ext_vector_type(8))) short bf16x8;   // 8 bf16 = 4 VGPRs
typedef __attribute__((ext_vector_type(4))) float f32x4;

// round-to-nearest-even f32 -> bf16 bits
__device__ __forceinline__ ushort f2bf(float f) {
    uint32_t u = __float_as_uint(f);
    u += 0x7fffu + ((u >> 16) & 1u);
    return (ushort)(u >> 16);
}

__device__ __forceinline__ f32x4 mfma16(bf16x8 a, bf16x8 b, f32x4 c) {
    return __builtin_amdgcn_mfma_f32_16x16x32_bf16(a, b, c, 0, 0, 0);
}

__device__ __forceinline__ bf16x8 pack8(float4 a, float4 b) {
    bf16x8 r;
    r[0] = (short)f2bf(a.x); r[1] = (short)f2bf(a.y);
    r[2] = (short)f2bf(a.z); r[3] = (short)f2bf(a.w);
    r[4] = (short)f2bf(b.x); r[5] = (short)f2bf(b.y);
    r[6] = (short)f2bf(b.z); r[7] = (short)f2bf(b.w);
    return r;
}

// ---------------------------------------------------------------------------
// Weight prep: fp32 src[K][N] -> bf16 dst[N][K] (transposed). Tiny, once/call.
// ---------------------------------------------------------------------------
__global__ void wtrans_kernel(const float* __restrict__ src,
                              ushort* __restrict__ dst, int K, int N) {
    int idx = blockIdx.x * 256 + threadIdx.x;
    if (idx < K * N) {
        int k = idx / N, n = idx % N;
        dst[n * K + k] = f2bf(src[idx]);
    }
}

// ---------------------------------------------------------------------------
// Fused kernel. One block = 64 rows (M-tile), 4 waves (wave w owns n in
// [64w,64w+64)).  h1^T = W1t(A) * x^T(B);  h2^T = W2t(A) * h1^T(B, LDS);
// lamb via in-register dot + shuffle/LDS reduce; inflows inline in fp32.
// MFMA 16x16x32 frags: A[m=lane&15][k=q*8+j], B[k=q*8+j][n=lane&15],
// C/D col=lane&15, row=q*4+reg  (verified layouts, guide §3).
// ---------------------------------------------------------------------------
__global__ __launch_bounds__(256) void mlp_kernel(
    const float* __restrict__ x,
    const float* __restrict__ T,
    const float* __restrict__ b1,
    const float* __restrict__ b2,
    const float* __restrict__ W3,
    const float* __restrict__ b3,
    const ushort* __restrict__ W1t,   // [256][32]  bf16, n1-major
    const ushort* __restrict__ W2t,   // [256][256] bf16, n2-major
    float* __restrict__ out) {
    constexpr int RS = 264;  // h1 row stride: 256+8 -> 16B rows, pad kills conflicts
    __shared__ ushort h1s[64 * RS];          // 33792 B
    __shared__ float b1f[256], b2f[256], w3f[256];
    __shared__ float lamb_part[4][64];
    __shared__ float sred[4][64], ired[4][64];

    const int tid  = threadIdx.x;
    const int w    = tid >> 6;
    const int lane = tid & 63;
    const int L    = lane & 15;
    const int q    = lane >> 4;
    const int m0   = blockIdx.x * 64;

    b1f[tid] = b1[tid];
    b2f[tid] = b2[tid];
    w3f[tid] = W3[tid];

    // ---- GEMM1 (K=32): A from bf16 W1t (global, L2-hot), B from fp32 x ----
    bf16x8 aw[4], bx[4];
#pragma unroll
    for (int i = 0; i < 4; ++i) {
        int n1 = 64 * w + i * 16 + L;
        aw[i] = *(const bf16x8*)(W1t + n1 * 32 + q * 8);
        const float4* xr = (const float4*)(x + (size_t)(m0 + i * 16 + L) * 32 + q * 8);
        bx[i] = pack8(xr[0], xr[1]);     // fp32 -> bf16 in-register (RNE)
    }
    f32x4 acc1[4][4];
#pragma unroll
    for (int i1 = 0; i1 < 4; ++i1)
#pragma unroll
        for (int im = 0; im < 4; ++im)
            acc1[i1][im] = mfma16(aw[i1], bx[im], (f32x4){0.f, 0.f, 0.f, 0.f});

    __syncthreads();  // b1f visible before use; h1s not yet read by anyone

    // fp32 bias + relu, THEN one bf16 rounding; pack 4 consecutive n1 -> b64 write
#pragma unroll
    for (int i1 = 0; i1 < 4; ++i1) {
        int n1b = 64 * w + i1 * 16 + q * 4;
#pragma unroll
        for (int im = 0; im < 4; ++im) {
            int m = im * 16 + L;
            float v0 = fmaxf(acc1[i1][im][0] + b1f[n1b + 0], 0.f);
            float v1 = fmaxf(acc1[i1][im][1] + b1f[n1b + 1], 0.f);
            float v2 = fmaxf(acc1[i1][im][2] + b1f[n1b + 2], 0.f);
            float v3 = fmaxf(acc1[i1][im][3] + b1f[n1b + 3], 0.f);
            uint2 pk;
            pk.x = (uint32_t)f2bf(v0) | ((uint32_t)f2bf(v1) << 16);
            pk.y = (uint32_t)f2bf(v2) | ((uint32_t)f2bf(v3) << 16);
            *reinterpret_cast<uint2*>(&h1s[m * RS + n1b]) = pk;
        }
    }
    __syncthreads();

    // ---- GEMM2 (K=256, 8 k-chunks): A from bf16 W2t global, B from LDS ----
    f32x4 acc2[4][4];
#pragma unroll
    for (int i2 = 0; i2 < 4; ++i2)
#pragma unroll
        for (int im = 0; im < 4; ++im) acc2[i2][im] = (f32x4){0.f, 0.f, 0.f, 0.f};

#pragma unroll
    for (int kc = 0; kc < 8; ++kc) {
        bf16x8 a2[4], bh[4];
#pragma unroll
        for (int i2 = 0; i2 < 4; ++i2) {
            int n2 = 64 * w + i2 * 16 + L;
            a2[i2] = *(const bf16x8*)(W2t + n2 * 256 + kc * 32 + q * 8);
        }
#pragma unroll
        for (int im = 0; im < 4; ++im) {
            int m = im * 16 + L;
            bh[im] = *(const bf16x8*)(&h1s[m * RS + kc * 32 + q * 8]);  // ds_read_b128
        }
#pragma unroll
        for (int i2 = 0; i2 < 4; ++i2)
#pragma unroll
            for (int im = 0; im < 4; ++im)
                acc2[i2][im] = mfma16(a2[i2], bh[im], acc2[i2][im]);
    }

    // ---- GEMM3: lamb[m] = sum_n2 relu(h2 + b2) * W3  (fp32 b2/W3, exact) ----
    float part[4] = {0.f, 0.f, 0.f, 0.f};
#pragma unroll
    for (int i2 = 0; i2 < 4; ++i2) {
        int n2b = 64 * w + i2 * 16 + q * 4;
#pragma unroll
        for (int im = 0; im < 4; ++im)
#pragma unroll
            for (int r = 0; r < 4; ++r) {
                float h2 = fmaxf(acc2[i2][im][r] + b2f[n2b + r], 0.f);
                part[im] = fmaf(h2, w3f[n2b + r], part[im]);
            }
    }
#pragma unroll
    for (int im = 0; im < 4; ++im) {
        float p = part[im];
        p += __shfl_xor(p, 16);
        p += __shfl_xor(p, 32);
        if (q == 0) lamb_part[w][im * 16 + L] = p;
    }

    // ---- inflows, exact fp32: row r handled by 4 threads (50 cp each) ----
    {
        int r = tid & 63, qq = tid >> 6;
        int gm = m0 + r;
        int b = gm / C_CNT, c = gm % C_CNT;
        const float* xb = x + (size_t)b * 6400;
        float as = 0.f, ai = 0.f;
        for (int cp = 50 * qq; cp < 50 * qq + 50; ++cp) {
            float tv = T[cp * C_CNT + c];                 // coalesced over r
            float2 si = *(const float2*)(xb + cp * 32);   // S,I adjacent; broadcast
            as = fmaf(si.x, tv, as);
            ai = fmaf(si.y, tv, ai);
        }
        sred[qq][r] = as;
        ired[qq][r] = ai;
    }
    __syncthreads();

    // ---- epilogue: one thread per row, all fp32 ----
    if (tid < 64) {
        int gm = m0 + tid;
        float lam = lamb_part[0][tid] + lamb_part[1][tid] +
                    lamb_part[2][tid] + lamb_part[3][tid] + b3[0];
        float2 si = *(const float2*)(x + (size_t)gm * 32);
        float S = si.x, I = si.y;
        int c = gm % C_CNT;
        float of = 1.0f - T[c * C_CNT + c];
        float sv = sred[0][tid] + sred[1][tid] + sred[2][tid] + sred[3][tid];
        float iv = ired[0][tid] + ired[1][tid] + ired[2][tid] + ired[3][tid];
        float dS = -lam * S + sv - of * S;
        float dI =  lam * S + iv - of * I;
        float2 o; o.x = S + dS; o.y = I + dI;
        ((float2*)out)[gm] = o;   // coalesced 8B store, covers out[2gm],out[2gm+1]
    }
}

// ---------------------------------------------------------------------------
extern "C" void kernel_launch(void* const* d_in, const int* in_sizes, int n_in,
                              void* d_out, int out_size, void* d_ws, size_t ws_size,
                              hipStream_t stream) {
    const float* x  = (const float*)d_in[0];
    const float* T  = (const float*)d_in[1];
    const float* W1 = (const float*)d_in[2];
    const float* b1 = (const float*)d_in[3];
    const float* W2 = (const float*)d_in[4];
    const float* b2 = (const float*)d_in[5];
    const float* W3 = (const float*)d_in[6];
    const float* b3 = (const float*)d_in[7];

    // ws: only 144 KB of transposed bf16 weights.
    ushort* W1t = (ushort*)d_ws;                       // 256*32  bf16 = 16 KB
    ushort* W2t = (ushort*)((char*)d_ws + 32 * 256 * 2); // 256*256 bf16 = 128 KB

    hipLaunchKernelGGL(wtrans_kernel, dim3(32),  dim3(256), 0, stream, W1, W1t, 32, 256);
    hipLaunchKernelGGL(wtrans_kernel, dim3(256), dim3(256), 0, stream, W2, W2t, 256, 256);
    hipLaunchKernelGGL(mlp_kernel, dim3(M_ROWS / 64), dim3(256), 0, stream,
                       x, T, b1, b2, W3, b3, W1t, W2t, (float*)d_out);
}

// Round 3
// 228.273 us; speedup vs baseline: 1.1814x; 1.1814x over previous
//
#include <hip/hip_runtime.h>
#include <hip/hip_bf16.h>
#include <stdint.h>

// Problem constants (from reference): B=2048, C=200, F=32, H=256.
// All tensors fp32. M = B*C = 409600 rows of 32 features, contiguous in x.
#define M_ROWS 409600
#define B_CNT  2048
#define C_CNT  200

typedef __attribute__((ext_vector_type(8))) short bf16x8;   // 8 bf16 = 4 VGPRs
typedef __attribute__((ext_vector_type(4))) float f32x4;

// round-to-nearest-even f32 -> bf16 bits
__device__ __forceinline__ ushort f2bf(float f) {
    uint32_t u = __float_as_uint(f);
    u += 0x7fffu + ((u >> 16) & 1u);
    return (ushort)(u >> 16);
}

__device__ __forceinline__ f32x4 mfma16(bf16x8 a, bf16x8 b, f32x4 c) {
    return __builtin_amdgcn_mfma_f32_16x16x32_bf16(a, b, c, 0, 0, 0);
}

__device__ __forceinline__ bf16x8 pack8(float4 a, float4 b) {
    bf16x8 r;
    r[0] = (short)f2bf(a.x); r[1] = (short)f2bf(a.y);
    r[2] = (short)f2bf(a.z); r[3] = (short)f2bf(a.w);
    r[4] = (short)f2bf(b.x); r[5] = (short)f2bf(b.y);
    r[6] = (short)f2bf(b.z); r[7] = (short)f2bf(b.w);
    return r;
}

// ---------------------------------------------------------------------------
// Prep kernel — ONE coalesced pass over x per batch row:
//   blocks [0,2048):   convert x row -> bf16 (optional), extract S/I (exact
//                      fp32, compact), compute sinflow/iinflow row (T coalesced)
//   blocks [2048,2304): W2^T -> bf16  (coalesced writes)
//   blocks [2304,2336): W1^T -> bf16
// ---------------------------------------------------------------------------
__global__ __launch_bounds__(256) void prep_kernel(
    const float* __restrict__ x, const float* __restrict__ T,
    const float* __restrict__ W1, const float* __restrict__ W2,
    ushort* __restrict__ xb16, float* __restrict__ Sc, float* __restrict__ Ic,
    float* __restrict__ sinW, float* __restrict__ iinW,
    ushort* __restrict__ W1t, ushort* __restrict__ W2t, int do_xb) {
    int blk = blockIdx.x, t = threadIdx.x;
    if (blk < B_CNT) {
        __shared__ float Sr[C_CNT], Ir[C_CNT];
        const float4* xr = (const float4*)(x + (size_t)blk * 6400);  // 1600 f4
        ushort4* xw = (ushort4*)(xb16 + (size_t)blk * 6400);
#pragma unroll
        for (int i = 0; i < 7; ++i) {
            int i4 = i * 256 + t;
            if (i4 < 1600) {
                float4 v = xr[i4];
                if (do_xb) {
                    ushort4 u;
                    u.x = f2bf(v.x); u.y = f2bf(v.y);
                    u.z = f2bf(v.z); u.w = f2bf(v.w);
                    xw[i4] = u;
                }
                if ((i4 & 7) == 0) {           // element i4*4 is feature 0 of c
                    int c = i4 >> 3;
                    Sr[c] = v.x; Ir[c] = v.y;
                    Sc[blk * C_CNT + c] = v.x;
                    Ic[blk * C_CNT + c] = v.y;
                }
            }
        }
        __syncthreads();
        if (t < C_CNT) {
            float as = 0.f, ai = 0.f;
            for (int cp = 0; cp < C_CNT; ++cp) {
                float tv = T[cp * C_CNT + t];        // coalesced over t, L2-hot
                as = fmaf(Sr[cp], tv, as);
                ai = fmaf(Ir[cp], tv, ai);
            }
            sinW[blk * C_CNT + t] = as;
            iinW[blk * C_CNT + t] = ai;
        }
    } else if (blk < B_CNT + 256) {
        int n = blk - B_CNT;                          // one n2 row per block
        W2t[n * 256 + t] = f2bf(W2[t * 256 + n]);     // write coalesced
    } else {
        int idx = (blk - B_CNT - 256) * 256 + t;      // 0..8191
        int n = idx >> 5, k = idx & 31;
        W1t[idx] = f2bf(W1[k * 256 + n]);
    }
}

// ---------------------------------------------------------------------------
// Fused MLP kernel. One block = 64 rows, 4 waves (wave w owns n in [64w,64w+64)).
// GEMM1: h1^T = W1t(A) * x^T(B);  GEMM2: h2^T = W2t(A) * h1^T(B from LDS);
// GEMM3: in-register dot with W3 + shuffle/LDS reduce. Epilogue from compact
// fp32 arrays (no strided x reads).
// MFMA 16x16x32 frags: A[m=lane&15][k=q*8+j], B[k=q*8+j][n=lane&15],
// C/D col=lane&15, row=q*4+reg.
// ---------------------------------------------------------------------------
template <bool XB>
__global__ __launch_bounds__(256, 4) void mlp_kernel(
    const float* __restrict__ x,
    const ushort* __restrict__ xb16,
    const float* __restrict__ T,
    const float* __restrict__ b1,
    const float* __restrict__ b2,
    const float* __restrict__ W3,
    const float* __restrict__ b3,
    const ushort* __restrict__ W1t,   // [256][32]  bf16, n1-major
    const ushort* __restrict__ W2t,   // [256][256] bf16, n2-major
    const float* __restrict__ Sc, const float* __restrict__ Ic,
    const float* __restrict__ sinW, const float* __restrict__ iinW,
    float* __restrict__ out) {
    constexpr int RS = 264;  // h1 row stride: 256+8, rows 16B-aligned, pad kills conflicts
    __shared__ ushort h1s[64 * RS];          // 33792 B
    __shared__ float b1f[256], b2f[256], w3f[256];
    __shared__ float lamb_part[4][64];

    const int tid  = threadIdx.x;
    const int w    = tid >> 6;
    const int lane = tid & 63;
    const int L    = lane & 15;
    const int q    = lane >> 4;
    const int m0   = blockIdx.x * 64;

    b1f[tid] = b1[tid];
    b2f[tid] = b2[tid];
    w3f[tid] = W3[tid];

    // ---- GEMM1 (K=32): A from bf16 W1t, B from bf16 xb16 (or fp32 x + pack)
    bf16x8 aw[4], bx[4];
#pragma unroll
    for (int i = 0; i < 4; ++i) {
        int n1 = 64 * w + i * 16 + L;
        aw[i] = *(const bf16x8*)(W1t + n1 * 32 + q * 8);
        if (XB) {
            bx[i] = *(const bf16x8*)(xb16 + (size_t)(m0 + i * 16 + L) * 32 + q * 8);
        } else {
            const float4* xr = (const float4*)(x + (size_t)(m0 + i * 16 + L) * 32 + q * 8);
            bx[i] = pack8(xr[0], xr[1]);
        }
    }
    f32x4 acc1[4][4];
#pragma unroll
    for (int i1 = 0; i1 < 4; ++i1)
#pragma unroll
        for (int im = 0; im < 4; ++im)
            acc1[i1][im] = mfma16(aw[i1], bx[im], (f32x4){0.f, 0.f, 0.f, 0.f});

    __syncthreads();  // b1f visible; h1s not yet read

    // fp32 bias + relu, one bf16 rounding; 4 consecutive n1 -> ds_write_b64
#pragma unroll
    for (int i1 = 0; i1 < 4; ++i1) {
        int n1b = 64 * w + i1 * 16 + q * 4;
#pragma unroll
        for (int im = 0; im < 4; ++im) {
            int m = im * 16 + L;
            float v0 = fmaxf(acc1[i1][im][0] + b1f[n1b + 0], 0.f);
            float v1 = fmaxf(acc1[i1][im][1] + b1f[n1b + 1], 0.f);
            float v2 = fmaxf(acc1[i1][im][2] + b1f[n1b + 2], 0.f);
            float v3 = fmaxf(acc1[i1][im][3] + b1f[n1b + 3], 0.f);
            uint2 pk;
            pk.x = (uint32_t)f2bf(v0) | ((uint32_t)f2bf(v1) << 16);
            pk.y = (uint32_t)f2bf(v2) | ((uint32_t)f2bf(v3) << 16);
            *reinterpret_cast<uint2*>(&h1s[m * RS + n1b]) = pk;
        }
    }
    __syncthreads();

    // ---- GEMM2 (K=256, 8 k-chunks): A from bf16 W2t (L2-hot), B from LDS ----
    f32x4 acc2[4][4];
#pragma unroll
    for (int i2 = 0; i2 < 4; ++i2)
#pragma unroll
        for (int im = 0; im < 4; ++im) acc2[i2][im] = (f32x4){0.f, 0.f, 0.f, 0.f};

#pragma unroll
    for (int kc = 0; kc < 8; ++kc) {
        bf16x8 a2[4], bh[4];
#pragma unroll
        for (int i2 = 0; i2 < 4; ++i2) {
            int n2 = 64 * w + i2 * 16 + L;
            a2[i2] = *(const bf16x8*)(W2t + n2 * 256 + kc * 32 + q * 8);
        }
#pragma unroll
        for (int im = 0; im < 4; ++im) {
            int m = im * 16 + L;
            bh[im] = *(const bf16x8*)(&h1s[m * RS + kc * 32 + q * 8]);  // ds_read_b128
        }
#pragma unroll
        for (int i2 = 0; i2 < 4; ++i2)
#pragma unroll
            for (int im = 0; im < 4; ++im)
                acc2[i2][im] = mfma16(a2[i2], bh[im], acc2[i2][im]);
    }

    // ---- GEMM3: lamb[m] = sum_n2 relu(h2 + b2) * W3 (fp32, exact) ----
    float part[4] = {0.f, 0.f, 0.f, 0.f};
#pragma unroll
    for (int i2 = 0; i2 < 4; ++i2) {
        int n2b = 64 * w + i2 * 16 + q * 4;
#pragma unroll
        for (int im = 0; im < 4; ++im)
#pragma unroll
            for (int r = 0; r < 4; ++r) {
                float h2 = fmaxf(acc2[i2][im][r] + b2f[n2b + r], 0.f);
                part[im] = fmaf(h2, w3f[n2b + r], part[im]);
            }
    }
#pragma unroll
    for (int im = 0; im < 4; ++im) {
        float p = part[im];
        p += __shfl_xor(p, 16);
        p += __shfl_xor(p, 32);
        if (q == 0) lamb_part[w][im * 16 + L] = p;
    }
    __syncthreads();

    // ---- epilogue: one thread per row, all reads compact & coalesced ----
    if (tid < 64) {
        int gm = m0 + tid;
        float lam = lamb_part[0][tid] + lamb_part[1][tid] +
                    lamb_part[2][tid] + lamb_part[3][tid] + b3[0];
        float S = Sc[gm], I = Ic[gm];
        int c = gm % C_CNT;
        float of = 1.0f - T[c * C_CNT + c];
        float sv = sinW[gm], iv = iinW[gm];
        float dS = -lam * S + sv - of * S;
        float dI =  lam * S + iv - of * I;
        float2 o; o.x = S + dS; o.y = I + dI;
        ((float2*)out)[gm] = o;   // coalesced 8B store -> out[2gm], out[2gm+1]
    }
}

// ---------------------------------------------------------------------------
extern "C" void kernel_launch(void* const* d_in, const int* in_sizes, int n_in,
                              void* d_out, int out_size, void* d_ws, size_t ws_size,
                              hipStream_t stream) {
    const float* x  = (const float*)d_in[0];
    const float* T  = (const float*)d_in[1];
    const float* W1 = (const float*)d_in[2];
    const float* b1 = (const float*)d_in[3];
    const float* W2 = (const float*)d_in[4];
    const float* b2 = (const float*)d_in[5];
    const float* W3 = (const float*)d_in[6];
    const float* b3 = (const float*)d_in[7];

    // ws layout: [xb16 (opt, 26.2 MB)] Sc Ic sin iin (4x1.64 MB) W1t W2t (144KB)
    const size_t xb_bytes = (size_t)M_ROWS * 32 * 2;
    const size_t f32_arr  = (size_t)M_ROWS * 4;
    const size_t small    = 4 * f32_arr + 8192 * 2 + 65536 * 2;
    const int    do_xb    = (ws_size >= xb_bytes + small) ? 1 : 0;

    char* ws = (char*)d_ws;
    ushort* xb16 = (ushort*)ws;
    char* base = ws + (do_xb ? xb_bytes : 0);
    float*  Sc   = (float*)(base);
    float*  Ic   = (float*)(base + f32_arr);
    float*  sinW = (float*)(base + 2 * f32_arr);
    float*  iinW = (float*)(base + 3 * f32_arr);
    ushort* W1t  = (ushort*)(base + 4 * f32_arr);
    ushort* W2t  = (ushort*)(base + 4 * f32_arr + 8192 * 2);

    hipLaunchKernelGGL(prep_kernel, dim3(B_CNT + 256 + 32), dim3(256), 0, stream,
                       x, T, W1, W2, xb16, Sc, Ic, sinW, iinW, W1t, W2t, do_xb);
    if (do_xb) {
        hipLaunchKernelGGL((mlp_kernel<true>), dim3(M_ROWS / 64), dim3(256), 0, stream,
                           x, xb16, T, b1, b2, W3, b3, W1t, W2t, Sc, Ic, sinW, iinW,
                           (float*)d_out);
    } else {
        hipLaunchKernelGGL((mlp_kernel<false>), dim3(M_ROWS / 64), dim3(256), 0, stream,
                           x, xb16, T, b1, b2, W3, b3, W1t, W2t, Sc, Ic, sinW, iinW,
                           (float*)d_out);
    }
}